// Round 1
// 429.751 us; speedup vs baseline: 1.0312x; 1.0312x over previous
//
#include <hip/hip_runtime.h>
#include <math.h>

// FanoCoupling, round 3: barrier-free wave-independent streaming.
//
// Key restructure vs round 2: flip MFMA orientation to D[z][batch]
// (A = W rows, B = s batch-columns). One wave owns 16 batches completely:
// it computes all 8 GEMV slots U0,U1,U3,U4,V1,V2,V3,V5 for its batches,
// so the line-combine is a per-lane register FMA -- no D tile in LDS,
// no per-tile __syncthreads, no phase serialization. Every wave streams
// loads/MFMA/stores independently; ~52KB of loads in flight per wave.
//
// C/D layout (m89-verified): col = lane&15 = batch, row = qg*4+r = z
// -> each lane's acc register quad is 4 CONSECUTIVE z for one batch,
//    so residual loads and output stores are float4.
//
// Lines: (0,1,2)(0,3,4)(0,5,6)(1,3,5)(4,1,6)(3,2,6)(4,2,5)
//   O2 = s2 + g0*(U0+V1+b)
//   O4 = s4 + g1*(U0+V3+b)
//   O5 = s5 + g3*(U1+V3+b) + g6*(U4+V2+b)
//   O6 = s6 + g2*(U0+V5+b) + g4*(U4+V1+b) + g5*(U3+V2+b)
//   O0,O1,O3 = pure copies (no line targets them).

using bf16x8  = __attribute__((ext_vector_type(8))) __bf16;
using floatx4 = __attribute__((ext_vector_type(4))) float;

#define TPW 4   // tiles (of 16 batches) per wave

__device__ __forceinline__ bf16x8 cvt8(floatx4 a, floatx4 b) {
    bf16x8 r;
    r[0]=(__bf16)a[0]; r[1]=(__bf16)a[1]; r[2]=(__bf16)a[2]; r[3]=(__bf16)a[3];
    r[4]=(__bf16)b[0]; r[5]=(__bf16)b[1]; r[6]=(__bf16)b[2]; r[7]=(__bf16)b[3];
    return r;
}

__global__ __launch_bounds__(256, 2)
void fano_kernel(const float* __restrict__ S,
                 const float* __restrict__ W,
                 const float* __restrict__ bias,
                 const float* __restrict__ gates,
                 float* __restrict__ out, int nt)
{
    // W as bf16, 64 rows (z) x 128 features; row = 16 units of 16B,
    // unit u of row z stored at u ^ (z&15) -> frag reads are 2-way max.
    __shared__ __align__(16) unsigned char Wb[64 * 256];   // 16 KiB

    const int tid  = threadIdx.x;
    const int lane = tid & 63;
    const int wave = tid >> 6;
    const int nl   = lane & 15;   // batch within tile (B-frag n) / W row low bits (A-frag m)
    const int qg   = lane >> 4;   // k-quad

    // ---- stage W -> LDS bf16, swizzled (once per block) ----
    #pragma unroll
    for (int k = 0; k < 4; ++k) {
        const int idx = tid + k * 256;
        const int z = idx >> 4, u = idx & 15;
        const float* src = W + z * 128 + u * 8;
        bf16x8 v = cvt8(*(const floatx4*)src, *(const floatx4*)(src + 4));
        *(bf16x8*)(Wb + z * 256 + ((u ^ (z & 15)) << 4)) = v;
    }

    // ---- gates softmax (uniform across threads) ----
    float g[7];
    {
        float mx = gates[0];
        #pragma unroll
        for (int i = 1; i < 7; ++i) mx = fmaxf(mx, gates[i]);
        float se = 0.f;
        #pragma unroll
        for (int i = 0; i < 7; ++i) { g[i] = __expf(gates[i] - mx); se += g[i]; }
        const float inv = 1.f / se;
        #pragma unroll
        for (int i = 0; i < 7; ++i) g[i] *= inv;
    }

    // ---- bias fragments in acc layout: bv[t] = bias[t*16 + qg*4 .. +3] ----
    floatx4 bv[4];
    #pragma unroll
    for (int t = 0; t < 4; ++t) bv[t] = *(const floatx4*)(bias + t * 16 + qg * 4);

    __syncthreads();   // the ONLY barrier; Wb is read-only afterwards

    const int wid = blockIdx.x * 4 + wave;

    for (int i = 0; i < TPW; ++i) {
        const int tile = wid * TPW + i;
        if (tile >= nt) break;

        const long long rb = ((long long)tile * 16 + nl) * 448;
        const float* srow = S + rb;
        float*       orow = out + rb;

        // -- issue B-operand source loads (colonies 0..5, fp32) --
        floatx4 tmp[6][4];
        #pragma unroll
        for (int c = 0; c < 6; ++c) {
            const float* p = srow + c * 64 + qg * 8;
            tmp[c][0] = *(const floatx4*)p;
            tmp[c][1] = *(const floatx4*)(p + 4);
            tmp[c][2] = *(const floatx4*)(p + 32);
            tmp[c][3] = *(const floatx4*)(p + 36);
        }
        // -- issue copy-colony loads {0,1,3} (overlaps the tmp wait) --
        floatx4 cp[3][4];
        #pragma unroll
        for (int j = 0; j < 3; ++j) {
            const int c = (j == 2) ? 3 : j;
            #pragma unroll
            for (int t = 0; t < 4; ++t)
                cp[j][t] = *(const floatx4*)(srow + c * 64 + t * 16 + qg * 4);
        }

        // -- convert to bf16 B-frags: sb[c][kb], lane holds s[nl][c][kb*32+qg*8+j] --
        bf16x8 sb[6][2];
        #pragma unroll
        for (int c = 0; c < 6; ++c) {
            sb[c][0] = cvt8(tmp[c][0], tmp[c][1]);
            sb[c][1] = cvt8(tmp[c][2], tmp[c][3]);
        }

        // -- pass-through colonies 0,1,3 --
        #pragma unroll
        for (int j = 0; j < 3; ++j) {
            const int c = (j == 2) ? 3 : j;
            #pragma unroll
            for (int t = 0; t < 4; ++t)
                *(floatx4*)(orow + c * 64 + t * 16 + qg * 4) = cp[j][t];
        }

        // -- issue residual loads {2,4,5,6}; consumed only after the MFMAs --
        floatx4 res[4][4];
        #pragma unroll
        for (int j = 0; j < 4; ++j) {
            const int c = (j == 0) ? 2 : (j == 1) ? 4 : (j == 2) ? 5 : 6;
            #pragma unroll
            for (int t = 0; t < 4; ++t)
                res[j][t] = *(const floatx4*)(srow + c * 64 + t * 16 + qg * 4);
        }

        // -- MFMA: z split in two halves to cap live accumulators at 64 VGPRs --
        // slots: 0=U0 1=U1 2=U3 3=U4 4=V1 5=V2 6=V3 7=V5
        #pragma unroll
        for (int hb = 0; hb < 2; ++hb) {
            floatx4 acc[8][2];
            #pragma unroll
            for (int s8 = 0; s8 < 8; ++s8) {
                acc[s8][0] = (floatx4){0.f,0.f,0.f,0.f};
                acc[s8][1] = (floatx4){0.f,0.f,0.f,0.f};
            }
            #pragma unroll
            for (int tp = 0; tp < 2; ++tp) {
                const int t    = hb * 2 + tp;
                const int rowb = (t * 16 + nl) * 256;
                #pragma unroll
                for (int h = 0; h < 4; ++h) {   // h: 32-feature block of W (0,1=U half; 2,3=V half)
                    const bf16x8 wf =
                        *(const bf16x8*)(Wb + rowb + (((h * 4 + qg) ^ nl) << 4));
                    const int kb = h & 1;       // matching 32-feature block of s
                    if (h < 2) {
                        acc[0][tp] = __builtin_amdgcn_mfma_f32_16x16x32_bf16(wf, sb[0][kb], acc[0][tp], 0,0,0);
                        acc[1][tp] = __builtin_amdgcn_mfma_f32_16x16x32_bf16(wf, sb[1][kb], acc[1][tp], 0,0,0);
                        acc[2][tp] = __builtin_amdgcn_mfma_f32_16x16x32_bf16(wf, sb[3][kb], acc[2][tp], 0,0,0);
                        acc[3][tp] = __builtin_amdgcn_mfma_f32_16x16x32_bf16(wf, sb[4][kb], acc[3][tp], 0,0,0);
                    } else {
                        acc[4][tp] = __builtin_amdgcn_mfma_f32_16x16x32_bf16(wf, sb[1][kb], acc[4][tp], 0,0,0);
                        acc[5][tp] = __builtin_amdgcn_mfma_f32_16x16x32_bf16(wf, sb[2][kb], acc[5][tp], 0,0,0);
                        acc[6][tp] = __builtin_amdgcn_mfma_f32_16x16x32_bf16(wf, sb[3][kb], acc[6][tp], 0,0,0);
                        acc[7][tp] = __builtin_amdgcn_mfma_f32_16x16x32_bf16(wf, sb[5][kb], acc[7][tp], 0,0,0);
                    }
                }
            }
            // -- register fold + store (per-lane: 4 consecutive z, batch nl) --
            #pragma unroll
            for (int tp = 0; tp < 2; ++tp) {
                const int t = hb * 2 + tp;
                const floatx4 b4 = bv[t];
                floatx4 o2 = res[0][t] + g[0] * (acc[0][tp] + acc[4][tp] + b4);
                floatx4 o4 = res[1][t] + g[1] * (acc[0][tp] + acc[6][tp] + b4);
                floatx4 o5 = res[2][t] + g[3] * (acc[1][tp] + acc[6][tp] + b4)
                                       + g[6] * (acc[3][tp] + acc[5][tp] + b4);
                floatx4 o6 = res[3][t] + g[2] * (acc[0][tp] + acc[7][tp] + b4)
                                       + g[4] * (acc[3][tp] + acc[4][tp] + b4)
                                       + g[5] * (acc[2][tp] + acc[5][tp] + b4);
                *(floatx4*)(orow + 2 * 64 + t * 16 + qg * 4) = o2;
                *(floatx4*)(orow + 4 * 64 + t * 16 + qg * 4) = o4;
                *(floatx4*)(orow + 5 * 64 + t * 16 + qg * 4) = o5;
                *(floatx4*)(orow + 6 * 64 + t * 16 + qg * 4) = o6;
            }
        }
    }
}

extern "C" void kernel_launch(void* const* d_in, const int* in_sizes, int n_in,
                              void* d_out, int out_size, void* d_ws, size_t ws_size,
                              hipStream_t stream) {
    const float* S     = (const float*)d_in[0];   // [B,7,64]
    const float* W     = (const float*)d_in[1];   // [64,128]
    const float* bias  = (const float*)d_in[2];   // [64]
    const float* gates = (const float*)d_in[3];   // [7]
    float* out = (float*)d_out;

    const int B  = in_sizes[0] / (7 * 64);        // 131072
    const int nt = B / 16;                        // 8192 tiles of 16 batches
    const int tiles_per_block = 4 * TPW;          // 4 waves x TPW tiles
    int grid = (nt + tiles_per_block - 1) / tiles_per_block;   // 512
    fano_kernel<<<grid, 256, 0, stream>>>(S, W, bias, gates, out, nt);
}

// Round 2
// 397.672 us; speedup vs baseline: 1.1144x; 1.0807x over previous
//
#include <hip/hip_runtime.h>
#include <math.h>

// FanoCoupling, round 4: fully-coalesced streaming + LDS transpose.
//
// Round-3 lesson: strided per-lane-batch global access (1792B lane stride)
// made every load/store 64 scattered segments -> txn-rate bound at 36% BW.
// Round 4 keeps the wave z-quarter MFMA split but routes ALL bulk traffic
// through coalesced float4 accesses; the batch<->z transposes happen in
// XOR-swizzled LDS (slot = unit ^ batch), double-buffered, 1 barrier/tile.
//
//   LDS tile: colonies 0..5 of 16 batches, f32: [c:6][b:16][slot:16][4] = 24KB
//   x2 buffers = 48KB -> 3 blocks/CU. T14 split: global loads for tile+1
//   issued at body top, ds_write at body end, __syncthreads once per tile.
//
//   wave w owns z rows [w*16, w*16+16):
//     wf[h] = W[z=w*16+nl][h*32+qg*8..+7]   (hoisted, 4 frags, global direct)
//     B-frag: s[b=nl][c][kb*32+qg*8..+7] via 2 swizzled ds_read_b128
//     16 MFMAs -> acc[8 slots] (U0,U1,U3,U4,V1,V2,V3,V5), D: lane=batch, 4 z
//   copies {0,1,3}: LDS -> coalesced store. res {2,4,5}: LDS acc-layout read.
//   colony 6: residual + store as 16x64B full segments (z-quad contiguous).
//
// Lines: O2=s2+g0*(U0+V1+b)  O4=s4+g1*(U0+V3+b)
//        O5=s5+g3*(U1+V3+b)+g6*(U4+V2+b)
//        O6=s6+g2*(U0+V5+b)+g4*(U4+V1+b)+g5*(U3+V2+b)

using bf16x8  = __attribute__((ext_vector_type(8))) __bf16;
using floatx4 = __attribute__((ext_vector_type(4))) float;

__device__ __forceinline__ bf16x8 cvt8(floatx4 a, floatx4 b) {
    bf16x8 r;
    r[0]=(__bf16)a[0]; r[1]=(__bf16)a[1]; r[2]=(__bf16)a[2]; r[3]=(__bf16)a[3];
    r[4]=(__bf16)b[0]; r[5]=(__bf16)b[1]; r[6]=(__bf16)b[2]; r[7]=(__bf16)b[3];
    return r;
}

// float index of 16B unit (c, row, slot) in one LDS buffer
#define LDSF(c, row, slot) ((((c) << 8) | ((row) << 4) | (slot)) << 2)

__global__ __launch_bounds__(256, 3)
void fano_kernel(const float* __restrict__ S,
                 const float* __restrict__ W,
                 const float* __restrict__ bias,
                 const float* __restrict__ gates,
                 float* __restrict__ out, int nt)
{
    __shared__ float buf[2][6144];    // 48 KiB total

    const int tid  = threadIdx.x;
    const int lane = tid & 63;
    const int w    = tid >> 6;        // wave = z-quarter
    const int nl   = lane & 15;       // batch (frag n / copy unit)
    const int qg   = lane >> 4;       // k-quad / batch-subrow
    const int bq   = w * 4 + qg;      // staging/copy batch row; ALSO z-quad idx

    // ---- gates softmax (uniform) ----
    float g[7];
    {
        float mx = gates[0];
        #pragma unroll
        for (int i = 1; i < 7; ++i) mx = fmaxf(mx, gates[i]);
        float se = 0.f;
        #pragma unroll
        for (int i = 0; i < 7; ++i) { g[i] = __expf(gates[i] - mx); se += g[i]; }
        const float inv = 1.f / se;
        #pragma unroll
        for (int i = 0; i < 7; ++i) g[i] *= inv;
    }

    // ---- bias frag: z = w*16 + qg*4 + r = bq*4 + r ----
    const floatx4 bv = *(const floatx4*)(bias + bq * 4);

    // ---- W frags (A operand), hoisted: lane holds z=w*16+nl, k=h*32+qg*8+j ----
    bf16x8 wf[4];
    #pragma unroll
    for (int h = 0; h < 4; ++h) {
        const float* p = W + (w * 16 + nl) * 128 + h * 32 + qg * 8;
        wf[h] = cvt8(*(const floatx4*)p, *(const floatx4*)(p + 4));
    }

    long long tile = blockIdx.x;
    if (tile >= nt) return;
    int cur = 0;

    // ---- prologue: stage tile 0 into buf[0] (coalesced load, swizzled write) ----
    {
        const float* sp = S + tile * 7168 + bq * 448;
        #pragma unroll
        for (int c = 0; c < 6; ++c) {
            floatx4 v = *(const floatx4*)(sp + c * 64 + nl * 4);
            *(floatx4*)(&buf[0][LDSF(c, bq, nl ^ bq)]) = v;
        }
    }
    __syncthreads();

    for (;;) {
        const long long next = tile + gridDim.x;
        const bool more = next < (long long)nt;
        const long long tb = tile * 7168;

        // -- T14 issue-early: next tile's coalesced loads (held in regs) --
        floatx4 stg[6];
        if (more) {
            const float* sp = S + next * 7168 + bq * 448;
            #pragma unroll
            for (int c = 0; c < 6; ++c)
                stg[c] = *(const floatx4*)(sp + c * 64 + nl * 4);
        }
        // -- colony-6 residual (16x64B full segments), issued early --
        const floatx4 res6 = *(const floatx4*)(S + tb + nl * 448 + 384 + bq * 4);

        const float* bc = buf[cur];

        // -- MFMA: 2 k-phases, B-frags from swizzled LDS --
        floatx4 acc[8];
        #pragma unroll
        for (int s8 = 0; s8 < 8; ++s8) acc[s8] = (floatx4){0.f, 0.f, 0.f, 0.f};
        #pragma unroll
        for (int kb = 0; kb < 2; ++kb) {
            bf16x8 sb[6];
            const int u0 = kb * 8 + qg * 2;
            #pragma unroll
            for (int c = 0; c < 6; ++c) {
                floatx4 f0 = *(const floatx4*)(bc + LDSF(c, nl, (u0    ) ^ nl));
                floatx4 f1 = *(const floatx4*)(bc + LDSF(c, nl, (u0 + 1) ^ nl));
                sb[c] = cvt8(f0, f1);
            }
            acc[0] = __builtin_amdgcn_mfma_f32_16x16x32_bf16(wf[kb],     sb[0], acc[0], 0,0,0);
            acc[1] = __builtin_amdgcn_mfma_f32_16x16x32_bf16(wf[kb],     sb[1], acc[1], 0,0,0);
            acc[2] = __builtin_amdgcn_mfma_f32_16x16x32_bf16(wf[kb],     sb[3], acc[2], 0,0,0);
            acc[3] = __builtin_amdgcn_mfma_f32_16x16x32_bf16(wf[kb],     sb[4], acc[3], 0,0,0);
            acc[4] = __builtin_amdgcn_mfma_f32_16x16x32_bf16(wf[2 + kb], sb[1], acc[4], 0,0,0);
            acc[5] = __builtin_amdgcn_mfma_f32_16x16x32_bf16(wf[2 + kb], sb[2], acc[5], 0,0,0);
            acc[6] = __builtin_amdgcn_mfma_f32_16x16x32_bf16(wf[2 + kb], sb[3], acc[6], 0,0,0);
            acc[7] = __builtin_amdgcn_mfma_f32_16x16x32_bf16(wf[2 + kb], sb[5], acc[7], 0,0,0);
        }

        // -- copies {0,1,3}: LDS -> coalesced global store --
        #pragma unroll
        for (int j = 0; j < 3; ++j) {
            const int c = (j == 2) ? 3 : j;
            floatx4 v = *(const floatx4*)(bc + LDSF(c, bq, nl ^ bq));
            *(floatx4*)(out + tb + bq * 448 + c * 64 + nl * 4) = v;
        }

        // -- residuals {2,4,5} in acc layout (row=nl batch, unit=bq z-quad) --
        const floatx4 r2 = *(const floatx4*)(bc + LDSF(2, nl, bq ^ nl));
        const floatx4 r4 = *(const floatx4*)(bc + LDSF(4, nl, bq ^ nl));
        const floatx4 r5 = *(const floatx4*)(bc + LDSF(5, nl, bq ^ nl));

        // -- fold + GEMV stores (16 x 64B full segments per instr) --
        floatx4 o2 = r2   + g[0] * (acc[0] + acc[4] + bv);
        floatx4 o4 = r4   + g[1] * (acc[0] + acc[6] + bv);
        floatx4 o5 = r5   + g[3] * (acc[1] + acc[6] + bv)
                          + g[6] * (acc[3] + acc[5] + bv);
        floatx4 o6 = res6 + g[2] * (acc[0] + acc[7] + bv)
                          + g[4] * (acc[3] + acc[4] + bv)
                          + g[5] * (acc[2] + acc[5] + bv);
        float* op = out + tb + nl * 448 + bq * 4;
        *(floatx4*)(op + 2 * 64) = o2;
        *(floatx4*)(op + 4 * 64) = o4;
        *(floatx4*)(op + 5 * 64) = o5;
        *(floatx4*)(op + 6 * 64) = o6;

        // -- T14 write-late: commit next tile into the other buffer --
        if (more) {
            float* bn = buf[cur ^ 1];
            #pragma unroll
            for (int c = 0; c < 6; ++c)
                *(floatx4*)(bn + LDSF(c, bq, nl ^ bq)) = stg[c];
        }
        __syncthreads();
        if (!more) break;
        tile = next;
        cur ^= 1;
    }
}

extern "C" void kernel_launch(void* const* d_in, const int* in_sizes, int n_in,
                              void* d_out, int out_size, void* d_ws, size_t ws_size,
                              hipStream_t stream) {
    const float* S     = (const float*)d_in[0];   // [B,7,64]
    const float* W     = (const float*)d_in[1];   // [64,128]
    const float* bias  = (const float*)d_in[2];   // [64]
    const float* gates = (const float*)d_in[3];   // [7]
    float* out = (float*)d_out;

    const int B  = in_sizes[0] / (7 * 64);        // 131072
    const int nt = B / 16;                        // 8192 tiles of 16 batches
    int grid = 768;                               // 3 blocks/CU, grid-stride
    if (grid > nt) grid = nt;
    fano_kernel<<<grid, 256, 0, stream>>>(S, W, bias, gates, out, nt);
}